// Round 4
// baseline (30.673 us; speedup 1.0000x reference)
//
#include <hip/hip_runtime.h>

#define NB 8
#define NI 16
#define NO 16
#define ND 512
#define ROWS 128                     // output rows per block
#define RT   (ND / ROWS)             // 4 row-tiles per (b,o)

typedef float f32x4 __attribute__((ext_vector_type(4)));   // native vector: OK for nontemporal builtin

// Fused kernel, grid = 128 (b,o) x 4 row-tiles = 512 blocks (2 per CU).
// Prologue: 256 threads process two i-rows at a time (thread halves), float4
// loads of x; halves combined through LDS. Produces colv (all 512 c), and
// rw/dg for this tile's 128 rows. Epilogue: stream 128x512 f32 tile with
// nontemporal float4 stores:
//   out[b,o,r,c] = y2[r]+y5+bias[o] + y3[c] + (r==c)*(y1[r]+y4)
__global__ __launch_bounds__(256) void leq_fused(
    const float* __restrict__ x, const float* __restrict__ weight,
    const float* __restrict__ bias, f32x4* __restrict__ out)
{
    const int blk = blockIdx.x;          // 0..511
    const int rt  = blk & (RT - 1);      // row tile within (b,o)
    const int bo  = blk >> 2;            // 0..127
    const int b   = bo >> 4;
    const int o   = bo & 15;
    const int t   = threadIdx.x;         // 0..255

    __shared__ __align__(16) float colvS[ND];          // y3 per c
    __shared__ __align__(16) float part1[ND];          // odd-i partials (y1)
    __shared__ __align__(16) float part2[ND];          // odd-i partials (y2)
    __shared__ __align__(16) float part3[ND];          // odd-i partials (y3)
    __shared__ float rwS[ROWS], dgS[ROWS];
    __shared__ float red4[4], red5[4];

    const float* wbase = weight + o * (5 * NI);
    const float* xb    = x + b * (NI * ND);
    const float  bia   = bias[o];

    const int half = t >> 7;             // 0: even i, 1: odd i
    const int fq   = t & 127;            // float4 index -> d in [4fq, 4fq+4)

    f32x4 a1 = {0,0,0,0}, a2 = {0,0,0,0}, a3 = {0,0,0,0};
    float p4 = 0.f, p5 = 0.f;

    #pragma unroll
    for (int i2 = 0; i2 < NI / 2; ++i2) {
        const int   i  = i2 * 2 + half;
        const float w0 = wbase[0 * NI + i];
        const float w1 = wbase[1 * NI + i];
        const float w2 = wbase[2 * NI + i];
        const float w3 = wbase[3 * NI + i];
        const float w4 = wbase[4 * NI + i];
        const f32x4 xv = reinterpret_cast<const f32x4*>(xb + i * ND)[fq];
        a1 += w0 * xv;
        a2 += w1 * xv;
        a3 += w2 * xv;
        const float xs = xv.x + xv.y + xv.z + xv.w;
        p4 += w3 * xs; p5 += w4 * xs;
    }

    if (half) {
        reinterpret_cast<f32x4*>(part1)[fq] = a1;
        reinterpret_cast<f32x4*>(part2)[fq] = a2;
        reinterpret_cast<f32x4*>(part3)[fq] = a3;
    }

    // p4/p5: wave shuffle reduce, then cross-wave via LDS
    #pragma unroll
    for (int off = 32; off > 0; off >>= 1) {
        p4 += __shfl_down(p4, off, 64);
        p5 += __shfl_down(p5, off, 64);
    }
    const int wave = t >> 6, lane = t & 63;
    if (lane == 0) { red4[wave] = p4; red5[wave] = p5; }
    __syncthreads();

    const float y4   = red4[0] + red4[1] + red4[2] + red4[3];
    const float y5   = red5[0] + red5[1] + red5[2] + red5[3];
    const float base = y5 + bia;

    if (half == 0) {
        const f32x4 o1 = reinterpret_cast<const f32x4*>(part1)[fq];
        const f32x4 o2 = reinterpret_cast<const f32x4*>(part2)[fq];
        const f32x4 o3 = reinterpret_cast<const f32x4*>(part3)[fq];
        reinterpret_cast<f32x4*>(colvS)[fq] = a3 + o3;
        if ((fq >> 5) == rt) {                 // this float4's rows are in our tile
            const int rl4 = (fq & 31) << 2;    // local row base
            const f32x4 rw = a2 + o2;
            const f32x4 dg = a1 + o1;
            rwS[rl4 + 0] = rw.x + base;
            rwS[rl4 + 1] = rw.y + base;
            rwS[rl4 + 2] = rw.z + base;
            rwS[rl4 + 3] = rw.w + base;
            dgS[rl4 + 0] = dg.x + y4;
            dgS[rl4 + 1] = dg.y + y4;
            dgS[rl4 + 2] = dg.z + y4;
            dgS[rl4 + 3] = dg.w + y4;
        }
    }
    __syncthreads();

    const f32x4* colv4 = reinterpret_cast<const f32x4*>(colvS);
    const int out_base = bo * (ND * (ND / 4)) + rt * ROWS * (ND / 4);

    #pragma unroll 4
    for (int k = 0; k < ROWS * (ND / 4) / 256; ++k) {   // 64 iterations
        const int idx = k * 256 + t;
        const int c4  = idx & 127;          // c / 4
        const int rl  = idx >> 7;           // local row
        const int r   = rt * ROWS + rl;

        const float  rv = rwS[rl];
        const float  dv = dgS[rl];
        const f32x4  cv = colv4[c4];

        const int dcol = r - (c4 << 2);     // in [0,3] iff diagonal in this float4
        f32x4 res;
        res.x = rv + cv.x + ((dcol == 0) ? dv : 0.0f);
        res.y = rv + cv.y + ((dcol == 1) ? dv : 0.0f);
        res.z = rv + cv.z + ((dcol == 2) ? dv : 0.0f);
        res.w = rv + cv.w + ((dcol == 3) ? dv : 0.0f);
        __builtin_nontemporal_store(res, &out[out_base + idx]);
    }
}

extern "C" void kernel_launch(void* const* d_in, const int* in_sizes, int n_in,
                              void* d_out, int out_size, void* d_ws, size_t ws_size,
                              hipStream_t stream) {
    const float* x      = (const float*)d_in[0];
    const float* weight = (const float*)d_in[1];
    const float* bias   = (const float*)d_in[2];

    leq_fused<<<NB * NO * RT, 256, 0, stream>>>(x, weight, bias, (f32x4*)d_out);
}

// Round 5
// 29.784 us; speedup vs baseline: 1.0298x; 1.0298x over previous
//
#include <hip/hip_runtime.h>

#define NB 8
#define NI 16
#define NO 16
#define ND 512
#define ROWS 32                      // output rows per block
#define RT   (ND / ROWS)             // 16 row-tiles per (b,o)

typedef float f32x4 __attribute__((ext_vector_type(4)));

// Fused kernel, grid = 128 (b,o) x 16 row-tiles = 2048 blocks (8 per CU).
// Prologue: thread halves each process 8 i-rows with float4 x loads; halves
// combined through LDS. Epilogue: stream this tile's 32x512 f32 output with
// plain float4 stores:
//   out[b,o,r,c] = y2[r]+y5+bias[o] + y3[c] + (r==c)*(y1[r]+y4)
__global__ __launch_bounds__(256, 8) void leq_fused(
    const float* __restrict__ x, const float* __restrict__ weight,
    const float* __restrict__ bias, f32x4* __restrict__ out)
{
    const int blk = blockIdx.x;          // 0..2047
    const int rt  = blk & (RT - 1);      // row tile within (b,o)
    const int bo  = blk >> 4;            // 0..127
    const int b   = bo >> 4;
    const int o   = bo & 15;
    const int t   = threadIdx.x;         // 0..255

    __shared__ __align__(16) float colvS[ND];          // y3 per c
    __shared__ __align__(16) float part1[ND];          // odd-i partials (y1)
    __shared__ __align__(16) float part2[ND];          // odd-i partials (y2)
    __shared__ __align__(16) float part3[ND];          // odd-i partials (y3)
    __shared__ float rwS[ROWS], dgS[ROWS];
    __shared__ float red4[4], red5[4];

    const float* wbase = weight + o * (5 * NI);
    const float* xb    = x + b * (NI * ND);
    const float  bia   = bias[o];

    const int half = t >> 7;             // 0: even i, 1: odd i
    const int fq   = t & 127;            // float4 index -> d in [4fq, 4fq+4)

    f32x4 a1 = {0,0,0,0}, a2 = {0,0,0,0}, a3 = {0,0,0,0};
    float p4 = 0.f, p5 = 0.f;

    #pragma unroll
    for (int i2 = 0; i2 < NI / 2; ++i2) {
        const int   i  = i2 * 2 + half;
        const float w0 = wbase[0 * NI + i];
        const float w1 = wbase[1 * NI + i];
        const float w2 = wbase[2 * NI + i];
        const float w3 = wbase[3 * NI + i];
        const float w4 = wbase[4 * NI + i];
        const f32x4 xv = reinterpret_cast<const f32x4*>(xb + i * ND)[fq];
        a1 += w0 * xv;
        a2 += w1 * xv;
        a3 += w2 * xv;
        const float xs = xv.x + xv.y + xv.z + xv.w;
        p4 += w3 * xs; p5 += w4 * xs;
    }

    if (half) {
        reinterpret_cast<f32x4*>(part1)[fq] = a1;
        reinterpret_cast<f32x4*>(part2)[fq] = a2;
        reinterpret_cast<f32x4*>(part3)[fq] = a3;
    }

    // p4/p5: wave shuffle reduce, then cross-wave via LDS
    #pragma unroll
    for (int off = 32; off > 0; off >>= 1) {
        p4 += __shfl_down(p4, off, 64);
        p5 += __shfl_down(p5, off, 64);
    }
    const int wave = t >> 6, lane = t & 63;
    if (lane == 0) { red4[wave] = p4; red5[wave] = p5; }
    __syncthreads();

    const float y4   = red4[0] + red4[1] + red4[2] + red4[3];
    const float y5   = red5[0] + red5[1] + red5[2] + red5[3];
    const float base = y5 + bia;

    if (half == 0) {
        const f32x4 o1 = reinterpret_cast<const f32x4*>(part1)[fq];
        const f32x4 o2 = reinterpret_cast<const f32x4*>(part2)[fq];
        const f32x4 o3 = reinterpret_cast<const f32x4*>(part3)[fq];
        reinterpret_cast<f32x4*>(colvS)[fq] = a3 + o3;
        if ((fq >> 3) == rt) {                 // this float4's rows are in our tile
            const int rl4 = (fq & 7) << 2;     // local row base
            const f32x4 rw = a2 + o2;
            const f32x4 dg = a1 + o1;
            rwS[rl4 + 0] = rw.x + base;
            rwS[rl4 + 1] = rw.y + base;
            rwS[rl4 + 2] = rw.z + base;
            rwS[rl4 + 3] = rw.w + base;
            dgS[rl4 + 0] = dg.x + y4;
            dgS[rl4 + 1] = dg.y + y4;
            dgS[rl4 + 2] = dg.z + y4;
            dgS[rl4 + 3] = dg.w + y4;
        }
    }
    __syncthreads();

    const f32x4* colv4 = reinterpret_cast<const f32x4*>(colvS);
    const int out_base = bo * (ND * (ND / 4)) + rt * ROWS * (ND / 4);

    #pragma unroll 4
    for (int k = 0; k < ROWS * (ND / 4) / 256; ++k) {   // 16 iterations
        const int idx = k * 256 + t;
        const int c4  = idx & 127;          // c / 4
        const int rl  = idx >> 7;           // local row
        const int r   = rt * ROWS + rl;

        const float  rv = rwS[rl];
        const float  dv = dgS[rl];
        const f32x4  cv = colv4[c4];

        const int dcol = r - (c4 << 2);     // in [0,3] iff diagonal in this float4
        f32x4 res;
        res.x = rv + cv.x + ((dcol == 0) ? dv : 0.0f);
        res.y = rv + cv.y + ((dcol == 1) ? dv : 0.0f);
        res.z = rv + cv.z + ((dcol == 2) ? dv : 0.0f);
        res.w = rv + cv.w + ((dcol == 3) ? dv : 0.0f);
        out[out_base + idx] = res;
    }
}

extern "C" void kernel_launch(void* const* d_in, const int* in_sizes, int n_in,
                              void* d_out, int out_size, void* d_ws, size_t ws_size,
                              hipStream_t stream) {
    const float* x      = (const float*)d_in[0];
    const float* weight = (const float*)d_in[1];
    const float* bias   = (const float*)d_in[2];

    leq_fused<<<NB * NO * RT, 256, 0, stream>>>(x, weight, bias, (f32x4*)d_out);
}

// Round 6
// 27.732 us; speedup vs baseline: 1.1061x; 1.0740x over previous
//
#include <hip/hip_runtime.h>

#define NB 8
#define NI 16
#define NO 16
#define ND 512
#define ROWS 32                      // output rows per block
#define RT   (ND / ROWS)             // 16 row-tiles per (b,o)

typedef float f32x4 __attribute__((ext_vector_type(4)));

// Fused kernel, grid = 128 (b,o) x 16 row-tiles = 2048 blocks.
// Prologue: thread halves each process 8 i-rows with float4 x loads; halves
// combined through LDS. Epilogue: stream this tile's 32x512 f32 output;
// the colv float4 is loop-invariant per thread (hoisted), so the unrolled
// loop is just: 2 wave-uniform LDS broadcasts + 8 VALU + 1 dwordx4 store.
//   out[b,o,r,c] = y2[r]+y5+bias[o] + y3[c] + (r==c)*(y1[r]+y4)
__global__ __launch_bounds__(256) void leq_fused(
    const float* __restrict__ x, const float* __restrict__ weight,
    const float* __restrict__ bias, f32x4* __restrict__ out)
{
    const int blk = blockIdx.x;          // 0..2047
    const int rt  = blk & (RT - 1);      // row tile within (b,o)
    const int bo  = blk >> 4;            // 0..127
    const int b   = bo >> 4;
    const int o   = bo & 15;
    const int t   = threadIdx.x;         // 0..255

    __shared__ __align__(16) float colvS[ND];          // y3 per c
    __shared__ __align__(16) float part1[ND];          // odd-i partials (y1)
    __shared__ __align__(16) float part2[ND];          // odd-i partials (y2)
    __shared__ __align__(16) float part3[ND];          // odd-i partials (y3)
    __shared__ float rwS[ROWS], dgS[ROWS];
    __shared__ float red4[4], red5[4];

    const float* wbase = weight + o * (5 * NI);
    const float* xb    = x + b * (NI * ND);
    const float  bia   = bias[o];

    const int half = t >> 7;             // 0: even i, 1: odd i
    const int fq   = t & 127;            // float4 index -> d in [4fq, 4fq+4)

    f32x4 a1 = {0,0,0,0}, a2 = {0,0,0,0}, a3 = {0,0,0,0};
    float p4 = 0.f, p5 = 0.f;

    #pragma unroll
    for (int i2 = 0; i2 < NI / 2; ++i2) {
        const int   i  = i2 * 2 + half;
        const float w0 = wbase[0 * NI + i];
        const float w1 = wbase[1 * NI + i];
        const float w2 = wbase[2 * NI + i];
        const float w3 = wbase[3 * NI + i];
        const float w4 = wbase[4 * NI + i];
        const f32x4 xv = reinterpret_cast<const f32x4*>(xb + i * ND)[fq];
        a1 += w0 * xv;
        a2 += w1 * xv;
        a3 += w2 * xv;
        const float xs = xv.x + xv.y + xv.z + xv.w;
        p4 += w3 * xs; p5 += w4 * xs;
    }

    if (half) {
        reinterpret_cast<f32x4*>(part1)[fq] = a1;
        reinterpret_cast<f32x4*>(part2)[fq] = a2;
        reinterpret_cast<f32x4*>(part3)[fq] = a3;
    }

    // p4/p5: wave shuffle reduce, then cross-wave via LDS
    #pragma unroll
    for (int off = 32; off > 0; off >>= 1) {
        p4 += __shfl_down(p4, off, 64);
        p5 += __shfl_down(p5, off, 64);
    }
    const int wave = t >> 6, lane = t & 63;
    if (lane == 0) { red4[wave] = p4; red5[wave] = p5; }
    __syncthreads();

    const float y4   = red4[0] + red4[1] + red4[2] + red4[3];
    const float y5   = red5[0] + red5[1] + red5[2] + red5[3];
    const float base = y5 + bia;

    if (half == 0) {
        const f32x4 o1 = reinterpret_cast<const f32x4*>(part1)[fq];
        const f32x4 o2 = reinterpret_cast<const f32x4*>(part2)[fq];
        const f32x4 o3 = reinterpret_cast<const f32x4*>(part3)[fq];
        reinterpret_cast<f32x4*>(colvS)[fq] = a3 + o3;
        if ((fq >> 3) == rt) {                 // this float4's rows are in our tile
            const int rl4 = (fq & 7) << 2;     // local row base
            const f32x4 rw = a2 + o2;
            const f32x4 dg = a1 + o1;
            rwS[rl4 + 0] = rw.x + base;
            rwS[rl4 + 1] = rw.y + base;
            rwS[rl4 + 2] = rw.z + base;
            rwS[rl4 + 3] = rw.w + base;
            dgS[rl4 + 0] = dg.x + y4;
            dgS[rl4 + 1] = dg.y + y4;
            dgS[rl4 + 2] = dg.z + y4;
            dgS[rl4 + 3] = dg.w + y4;
        }
    }
    __syncthreads();

    // ---- store phase: c4 is loop-invariant per thread; cv hoisted ----
    const int   c4    = t & 127;
    const f32x4 cv    = reinterpret_cast<const f32x4*>(colvS)[c4];
    const int   cbase = c4 << 2;               // column of res.x
    const int   out_base = bo * (ND * (ND / 4)) + rt * ROWS * (ND / 4);
    const int   rbase = rt * ROWS;

    #pragma unroll
    for (int k = 0; k < 16; ++k) {
        const int rl = (k << 1) + half;        // 0..31, wave-uniform
        const float rv = rwS[rl];              // LDS broadcast
        const float dv = dgS[rl];              // LDS broadcast
        const int dcol = (rbase + rl) - cbase; // in [0,3] iff diag in this float4
        f32x4 res;
        res.x = rv + cv.x + ((dcol == 0) ? dv : 0.0f);
        res.y = rv + cv.y + ((dcol == 1) ? dv : 0.0f);
        res.z = rv + cv.z + ((dcol == 2) ? dv : 0.0f);
        res.w = rv + cv.w + ((dcol == 3) ? dv : 0.0f);
        out[out_base + (rl << 7) + c4] = res;
    }
}

extern "C" void kernel_launch(void* const* d_in, const int* in_sizes, int n_in,
                              void* d_out, int out_size, void* d_ws, size_t ws_size,
                              hipStream_t stream) {
    const float* x      = (const float*)d_in[0];
    const float* weight = (const float*)d_in[1];
    const float* bias   = (const float*)d_in[2];

    leq_fused<<<NB * NO * RT, 256, 0, stream>>>(x, weight, bias, (f32x4*)d_out);
}